// Round 8
// baseline (386.869 us; speedup 1.0000x reference)
//
#include <hip/hip_runtime.h>

// Problem constants (fixed by the reference):
constexpr int   T_ = 1000, B_ = 64, C_ = 512, S_ = 100;
constexpr int   L_ = 2 * S_ + 1;       // 201 extended states
constexpr float NEGF = -1e30f;
constexpr int   R_ = 16;               // LDS ring depth (rows)
constexpr int   SLOTB = 1024;          // bytes per ring slot (pow2 for wrap)
constexpr int   ENT_BLOCKS = 1984;     // entropy blocks (grid = 64 + 1984 = 2048)
constexpr int   ENT_W = ENT_BLOCKS * 4;          // 7936 entropy wave slots
constexpr int   WS_N  = ENT_W + B_;              // + 64 CTC slots
constexpr float K2    = 1.44269504088896340736f; // log2(e)
constexpr float LN2   = 0.69314718055994530942f;

typedef __attribute__((address_space(1))) const void gvoid;
typedef __attribute__((address_space(3))) void       lvoid;

// raw v_exp_f32 (2^x). HIP has no __exp2f device intrinsic.
__device__ __forceinline__ float fexp2(float x) {
#if __has_builtin(__builtin_amdgcn_exp2f)
  return __builtin_amdgcn_exp2f(x);
#else
  float r; asm("v_exp_f32 %0, %1" : "=v"(r) : "v"(x)); return r;
#endif
}

// base-2 log-add-exp; 2-arg form uses min-trick (1 exp2 instead of 2)
__device__ __forceinline__ float l2ae2(float a, float b) {
  float m = fmaxf(a, b);
  float d = fminf(a, b) - m;            // <= 0
  return m + __log2f(1.0f + fexp2(d));
}
__device__ __forceinline__ float l2ae3(float a, float b, float c) {
  float m = fmaxf(fmaxf(a, b), c);
  return m + __log2f(fexp2(a - m) + fexp2(b - m) + fexp2(c - m));
}

__global__ __launch_bounds__(256) void ctc_fused_kernel(
    const float* __restrict__ lp,        // (T,B,C) log-probs
    const int*   __restrict__ targets,   // (B,S)
    const int*   __restrict__ in_len,    // (B,)
    const int*   __restrict__ tgt_len,   // (B,)
    float*       __restrict__ ws) {      // WS_N partial slots
  const int bid = blockIdx.x;
  __shared__ char lds[R_ * SLOTB];       // 16 KB ring (CTC blocks only use it)

  if (bid < B_) {
    // ---------------- CTC alpha recursion: one batch row per block, wave 0 only
    if (threadIdx.x >= 64) return;
    const int lane = threadIdx.x;
    const int b = bid;
    const int* tgt = targets + b * S_;

    const int s0 = lane * 4;            // this lane owns states s0..s0+3
    const int i1 = lane * 2;            // target idx for odd state s0+1
    const int e1 = (s0 + 1 < L_) ? tgt[i1] : 0;
    const int e3 = (s0 + 3 < L_) ? tgt[i1 + 1] : 0;
    const int ep = (lane > 0 && (i1 - 1) < S_) ? tgt[i1 - 1] : 0; // ext[s0-1]
    const bool sk1 = (s0 + 1 >= 2) && (e1 != 0) && (e1 != ep);
    const bool sk3 = (e3 != 0) && (e3 != e1);   // s0+3 >= 2 always

    const int len = in_len[b];
    const int tl  = tgt_len[b];

    const float* base = lp + (size_t)b * C_;    // row t: base + t*(B_*C_)

    // t = 0 init (base-2 domain). Plain loads complete (compiler-waited) here.
    float i0  = base[0];
    float i1v = base[e1];
    float a0 = (lane == 0) ? i0 * K2  : NEGF;
    float a1 = (lane == 0) ? i1v * K2 : NEGF;
    float a2 = NEGF, a3 = NEGF;
    asm volatile("" :: "v"(a0), "v"(a1));
    asm volatile("" :: "s"(len), "s"(tl));

    const int lane4 = lane * 4;          // LDS read base within a slot

    __builtin_amdgcn_s_setprio(1);

    // ---- prologue: DMA rows 1..16 into slots 1..15,0 (3 gathers per row) ----
#pragma unroll
    for (int r = 1; r <= R_; ++r) {
      const float* rowp = base + (size_t)r * (B_ * C_);
      char* l0 = lds + (r & (R_ - 1)) * SLOTB;
      __builtin_amdgcn_global_load_lds((gvoid*)rowp,        (lvoid*)l0,         4, 0, 0);
      __builtin_amdgcn_global_load_lds((gvoid*)(rowp + e1), (lvoid*)(l0 + 256), 4, 0, 0);
      __builtin_amdgcn_global_load_lds((gvoid*)(rowp + e3), (lvoid*)(l0 + 512), 4, 0, 0);
    }
    const float* rowp = base + (size_t)(R_ + 1) * (B_ * C_);  // next row to stage: 17

    // ping-pong register sets: A = odd t rows, B = even t rows
    float pbA, p1A, p3A, pbB, p1B, p3B;
    asm volatile("s_waitcnt vmcnt(45)" ::: "memory");   // row 1 done (rows 2..16 = 45 ops)
    __builtin_amdgcn_sched_barrier(0);
    asm volatile("ds_read_b32 %0, %3 offset:0\n\t"
                 "ds_read_b32 %1, %3 offset:256\n\t"
                 "ds_read_b32 %2, %3 offset:512"
                 : "=&v"(pbA), "=&v"(p1A), "=&v"(p3A)
                 : "v"(lane4 + 1 * SLOTB));
    asm volatile("s_waitcnt vmcnt(42)" ::: "memory");   // row 2 done
    __builtin_amdgcn_sched_barrier(0);
    asm volatile("ds_read_b32 %0, %3 offset:0\n\t"
                 "ds_read_b32 %1, %3 offset:256\n\t"
                 "ds_read_b32 %2, %3 offset:512"
                 : "=&v"(pbB), "=&v"(p1B), "=&v"(p3B)
                 : "v"(lane4 + 2 * SLOTB));

    int t = 1;
    int rowg   = R_ + 1;        // row staged by the next phase (17)
    int rd_off = 3 * SLOTB;     // slot of row t+2 (ds_read prefetch target)
    int wr_off = 1 * SLOTB;     // slot of row t+16 (= slot t&15)

    // One phase: consume set P (row t), stage row t+16, prefetch-read row t+2 into P.
#define PHASE(PB, P1, P3) { \
    asm volatile("s_waitcnt lgkmcnt(3)" ::: "memory"); \
    __builtin_amdgcn_sched_barrier(0); \
    if (t < len) {  /* uniform branch: t,len wave-uniform */ \
      const float lpb = PB * K2, lp1v = P1 * K2, lp3v = P3 * K2; \
      float up1 = __shfl_up(a3, 1); \
      if (lane == 0) up1 = NEGF; \
      float n0 = l2ae2(a0, up1); \
      float n1 = l2ae3(a1, a0, sk1 ? up1 : NEGF); \
      float n2 = l2ae2(a2, a1); \
      float n3 = l2ae3(a3, a2, sk3 ? a1 : NEGF); \
      a0 = n0 + lpb; a1 = n1 + lp1v; a2 = n2 + lpb; a3 = n3 + lp3v; \
    } \
    { char* l0 = lds + wr_off; \
      __builtin_amdgcn_global_load_lds((gvoid*)rowp,        (lvoid*)l0,         4, 0, 0); \
      __builtin_amdgcn_global_load_lds((gvoid*)(rowp + e1), (lvoid*)(l0 + 256), 4, 0, 0); \
      __builtin_amdgcn_global_load_lds((gvoid*)(rowp + e3), (lvoid*)(l0 + 512), 4, 0, 0); \
      if (rowg < T_ - 1) { rowp += B_ * C_; ++rowg; } \
      wr_off = (wr_off + SLOTB) & (R_ * SLOTB - 1); } \
    asm volatile("s_waitcnt vmcnt(42)" ::: "memory");  /* row t+2 staged */ \
    __builtin_amdgcn_sched_barrier(0); \
    asm volatile("ds_read_b32 %0, %3 offset:0\n\t" \
                 "ds_read_b32 %1, %3 offset:256\n\t" \
                 "ds_read_b32 %2, %3 offset:512" \
                 : "=&v"(PB), "=&v"(P1), "=&v"(P3) \
                 : "v"(lane4 + rd_off)); \
    rd_off = (rd_off + SLOTB) & (R_ * SLOTB - 1); \
    ++t; }

#pragma clang loop unroll(disable)
    for (int it = 0; it < 504; ++it) {   // 1008 steps, masked past len
      PHASE(pbA, p1A, p3A)               // odd t
      PHASE(pbB, p1B, p3B)               // even t
    }
#undef PHASE

    asm volatile("s_waitcnt vmcnt(0) lgkmcnt(0)" ::: "memory");
    __builtin_amdgcn_s_setprio(0);

    // final: ll = ln2 * l2ae2(ahat[2*tl], ahat[2*tl-1]) via shuffles (tl uniform)
    const int last = 2 * tl;
    const int lane_hi = last >> 2,       sub_hi = last & 3;
    const int lane_lo = (last - 1) >> 2, sub_lo = (last - 1) & 3;
    float cand_hi = (sub_hi == 0) ? a0 : (sub_hi == 1) ? a1 : (sub_hi == 2) ? a2 : a3;
    float cand_lo = (sub_lo == 0) ? a0 : (sub_lo == 1) ? a1 : (sub_lo == 2) ? a2 : a3;
    float vhi = __shfl(cand_hi, lane_hi);
    float vlo = __shfl(cand_lo, lane_lo);
    if (lane == 0) {
      float ll = LN2 * l2ae2(vhi, vlo);
      float nll = -ll;
      if (nll > 1e29f) nll = 0.0f;
      ws[ENT_W + b] = 0.9f * nll / ((float)tl * (float)B_);
    }
  } else {
    // ---------------- entropy term: grid-stride float4 sweep of all T*B*C
    const int ebid = bid - B_;
    const size_t tid = (size_t)ebid * blockDim.x + threadIdx.x;
    const size_t nthreads = (size_t)ENT_BLOCKS * blockDim.x;
    const float4* v = (const float4*)lp;
    const size_t n4 = (size_t)T_ * B_ * C_ / 4;
    float s = 0.0f;
    for (size_t i = tid; i < n4; i += nthreads) {
      float4 x = v[i];
      s += __expf(x.x) * x.x + __expf(x.y) * x.y
         + __expf(x.z) * x.z + __expf(x.w) * x.w;
    }
    // wave reduce, one plain store per wave (no atomics)
    for (int o = 32; o > 0; o >>= 1) s += __shfl_down(s, o);
    if ((threadIdx.x & 63) == 0) {
      const int wslot = ebid * 4 + (int)(threadIdx.x >> 6);
      ws[wslot] = s;   // raw partial of sum(exp(lp)*lp)
    }
  }
}

__global__ __launch_bounds__(256) void finalize_kernel(
    const float* __restrict__ ws, float* __restrict__ out) {
  const float entScale = 0.1f / ((float)T_ * (float)B_);
  float acc = 0.0f;
  for (int i = threadIdx.x; i < WS_N; i += 256) {
    float v = ws[i];
    acc += (i < ENT_W) ? v * entScale : v;
  }
  // block reduce: wave shuffle + LDS across 4 waves
  for (int o = 32; o > 0; o >>= 1) acc += __shfl_down(acc, o);
  __shared__ float red[4];
  if ((threadIdx.x & 63) == 0) red[threadIdx.x >> 6] = acc;
  __syncthreads();
  if (threadIdx.x == 0) out[0] = red[0] + red[1] + red[2] + red[3];
}

extern "C" void kernel_launch(void* const* d_in, const int* in_sizes, int n_in,
                              void* d_out, int out_size, void* d_ws, size_t ws_size,
                              hipStream_t stream) {
  const float* lp  = (const float*)d_in[0];
  const int*   tg  = (const int*)d_in[1];
  const int*   il  = (const int*)d_in[2];
  const int*   tl  = (const int*)d_in[3];
  float*       ws  = (float*)d_ws;
  float*       out = (float*)d_out;

  dim3 grid(B_ + ENT_BLOCKS), block(256);
  ctc_fused_kernel<<<grid, block, 0, stream>>>(lp, tg, il, tl, ws);
  finalize_kernel<<<1, 256, 0, stream>>>(ws, out);
}

// Round 9
// 330.429 us; speedup vs baseline: 1.1708x; 1.1708x over previous
//
#include <hip/hip_runtime.h>

// Problem constants (fixed by the reference):
constexpr int   T_ = 1000, B_ = 64, C_ = 512, S_ = 100;
constexpr int   L_ = 2 * S_ + 1;       // 201 extended states
constexpr float NEGF = -1e30f;
constexpr int   SS   = 32;             // rows per super-step
constexpr int   NSS  = (T_ + SS - 1) / SS;   // 32 (last super-step has 8 rows)
constexpr int   NPROD = 7;             // producer waves per block
constexpr float K2   = 1.44269504088896340736f; // log2(e)
constexpr float LN2  = 0.69314718055994530942f;
constexpr float ENT_SCALE = 0.1f / ((float)T_ * (float)B_);

// raw v_exp_f32 (2^x). HIP has no __exp2f device intrinsic.
__device__ __forceinline__ float fexp2(float x) {
#if __has_builtin(__builtin_amdgcn_exp2f)
  return __builtin_amdgcn_exp2f(x);
#else
  float r; asm("v_exp_f32 %0, %1" : "=v"(r) : "v"(x)); return r;
#endif
}

// base-2 log-add-exp; 2-arg form uses min-trick (1 exp2 instead of 2)
__device__ __forceinline__ float l2ae2(float a, float b) {
  float m = fmaxf(a, b);
  float d = fminf(a, b) - m;            // <= 0
  return m + __log2f(1.0f + fexp2(d));
}
__device__ __forceinline__ float l2ae3(float a, float b, float c) {
  float m = fmaxf(fmaxf(a, b), c);
  return m + __log2f(fexp2(a - m) + fexp2(b - m) + fexp2(c - m));
}

// Producer helper: stream one row (512 floats) coalesced, accumulate entropy,
// store the full row into the LDS slot.
#define PROD_ROW(BI, R, R0)  { \
    const float* rp = base + (size_t)(R) * (B_ * C_); \
    float4 x = *(const float4*)(rp + lane * 4); \
    float4 y = *(const float4*)(rp + 256 + lane * 4); \
    ent += __expf(x.x)*x.x + __expf(x.y)*x.y + __expf(x.z)*x.z + __expf(x.w)*x.w \
         + __expf(y.x)*y.x + __expf(y.y)*y.y + __expf(y.z)*y.z + __expf(y.w)*y.w; \
    const int s = (R) - (R0); \
    *(float4*)&buf[BI][s][lane * 4] = x; \
    *(float4*)&buf[BI][s][256 + lane * 4] = y; \
  }

__global__ __launch_bounds__(512) void ctc_pc_kernel(
    const float* __restrict__ lp,        // (T,B,C) log-probs
    const int*   __restrict__ targets,   // (B,S)
    const int*   __restrict__ in_len,    // (B,)
    const int*   __restrict__ tgt_len,   // (B,)
    float*       __restrict__ ws) {      // NPROD*B_ entropy partials + B_ nll
  const int b    = blockIdx.x;           // one block per batch row
  const int tid  = (int)threadIdx.x;
  const int wave = tid >> 6;
  const int lane = tid & 63;
  __shared__ float buf[2][SS][C_];       // 2 x 32 rows x 2KB = 128 KB

  const float* base = lp + (size_t)b * C_;   // row t at base + t*B_*C_

  if (wave == 0) {
    // ---------------- consumer: alpha recursion over LDS-staged rows ----------
    const int* tgt = targets + b * S_;
    const int s0 = lane * 4;            // this lane owns states s0..s0+3
    const int i1 = lane * 2;
    const int e1 = (s0 + 1 < L_) ? tgt[i1] : 0;
    const int e3 = (s0 + 3 < L_) ? tgt[i1 + 1] : 0;
    const int ep = (lane > 0 && (i1 - 1) < S_) ? tgt[i1 - 1] : 0; // ext[s0-1]
    const bool sk1 = (s0 + 1 >= 2) && (e1 != 0) && (e1 != ep);
    const bool sk3 = (e3 != 0) && (e3 != e1);   // s0+3 >= 2 always
    const int len = in_len[b];
    const int tl  = tgt_len[b];

    float a0 = NEGF, a1 = NEGF, a2 = NEGF, a3 = NEGF;
    __syncthreads();                    // buf[0] ready
    __builtin_amdgcn_s_setprio(1);      // consumer is the critical path
    int cur = 0, t = 0;
    for (int ssi = 0; ssi < NSS; ++ssi) {
      const int cnt = (ssi == NSS - 1) ? (T_ - SS * (NSS - 1)) : SS;
#pragma unroll 4
      for (int s = 0; s < cnt; ++s, ++t) {
        const float pbv = buf[cur][s][0];    // blank (broadcast)
        const float p1v = buf[cur][s][e1];   // LDS gather
        const float p3v = buf[cur][s][e3];
        if (t == 0) {
          a0 = (lane == 0) ? pbv * K2 : NEGF;
          a1 = (lane == 0) ? p1v * K2 : NEGF;
        } else if (t < len) {                // uniform branch
          const float lpb = pbv * K2, lp1v = p1v * K2, lp3v = p3v * K2;
          float up1 = __shfl_up(a3, 1);
          if (lane == 0) up1 = NEGF;
          float n0 = l2ae2(a0, up1);
          float n1 = l2ae3(a1, a0, sk1 ? up1 : NEGF);
          float n2 = l2ae2(a2, a1);
          float n3 = l2ae3(a3, a2, sk3 ? a1 : NEGF);
          a0 = n0 + lpb; a1 = n1 + lp1v; a2 = n2 + lpb; a3 = n3 + lp3v;
        }
      }
      __syncthreads();                  // super-step boundary
      cur ^= 1;
    }
    __builtin_amdgcn_s_setprio(0);

    // readout: ll = ln2 * l2ae2(ahat[2*tl], ahat[2*tl-1]) (tl wave-uniform)
    const int last = 2 * tl;
    const int lane_hi = last >> 2,       sub_hi = last & 3;
    const int lane_lo = (last - 1) >> 2, sub_lo = (last - 1) & 3;
    float cand_hi = (sub_hi == 0) ? a0 : (sub_hi == 1) ? a1 : (sub_hi == 2) ? a2 : a3;
    float cand_lo = (sub_lo == 0) ? a0 : (sub_lo == 1) ? a1 : (sub_lo == 2) ? a2 : a3;
    float vhi = __shfl(cand_hi, lane_hi);
    float vlo = __shfl(cand_lo, lane_lo);
    if (lane == 0) {
      float ll = LN2 * l2ae2(vhi, vlo);
      float nll = -ll;
      if (nll > 1e29f) nll = 0.0f;
      ws[NPROD * B_ + b] = 0.9f * nll / ((float)tl * (float)B_);
    }
  } else {
    // ---------------- producers (waves 1..7): stream + entropy + LDS stage ----
    const int pw = wave - 1;             // 0..6
    float ent = 0.0f;
    // prologue: fill super-step 0 into buf[0]
    {
      const int r1 = (SS < T_) ? SS : T_;
#pragma unroll 4
      for (int r = pw; r < r1; r += NPROD) PROD_ROW(0, r, 0)
    }
    __syncthreads();
    int cur = 0;
    for (int ssi = 0; ssi < NSS; ++ssi) {
      if (ssi + 1 < NSS) {
        const int r0 = (ssi + 1) * SS;
        const int r1 = (r0 + SS < T_) ? (r0 + SS) : T_;
        const int bi = cur ^ 1;
#pragma unroll 4
        for (int r = r0 + pw; r < r1; r += NPROD) PROD_ROW(bi, r, r0)
      }
      __syncthreads();
      cur ^= 1;
    }
    // entropy partial: wave-reduce, one plain store per wave
    for (int o = 32; o > 0; o >>= 1) ent += __shfl_down(ent, o);
    if (lane == 0) ws[b * NPROD + pw] = ent;   // raw sum(exp(lp)*lp) partial
  }
}

__global__ __launch_bounds__(64) void finalize_kernel(
    const float* __restrict__ ws, float* __restrict__ out) {
  const int tid = (int)threadIdx.x;
  float acc = 0.0f;
  for (int i = tid; i < NPROD * B_ + B_; i += 64) {
    float v = ws[i];
    acc += (i < NPROD * B_) ? v * ENT_SCALE : v;
  }
  for (int o = 32; o > 0; o >>= 1) acc += __shfl_down(acc, o);
  if (tid == 0) out[0] = acc;
}

extern "C" void kernel_launch(void* const* d_in, const int* in_sizes, int n_in,
                              void* d_out, int out_size, void* d_ws, size_t ws_size,
                              hipStream_t stream) {
  const float* lp  = (const float*)d_in[0];
  const int*   tg  = (const int*)d_in[1];
  const int*   il  = (const int*)d_in[2];
  const int*   tl  = (const int*)d_in[3];
  float*       ws  = (float*)d_ws;
  float*       out = (float*)d_out;

  ctc_pc_kernel<<<dim3(B_), dim3(512), 0, stream>>>(lp, tg, il, tl, ws);
  finalize_kernel<<<dim3(1), dim3(64), 0, stream>>>(ws, out);
}